// Round 4
// baseline (660.381 us; speedup 1.0000x reference)
//
#include <hip/hip_runtime.h>

// DistributionLoss: local 7x7xC std (zero-padded) of two [16,3,512,512] fp32
// tensors, smooth-L1 mean between std maps -> scalar.
//
// R4: branch-free register-resident design, both inputs interleaved.
// Each thread computes a 4x4 output patch for BOTH inputs simultaneously.
// Per row iteration: gy clamped (loads always legal, always issued), 18
// independent float4 loads (2 inputs x 3 ch x 3 groups), channel reduce,
// sliding 7-tap horizontal, out-of-range rows nulled via 0/1 mask multiply
// (exact: contributions are linear). No branches inside the unrolled row
// loop -> loads from later iterations can hoist above earlier compute.

#define K   7
#define PAD 3
#define NY  4
#define NT  256

__global__ __launch_bounds__(NT, 4) void dist_loss_kernel(
    const float* __restrict__ pred,
    const float* __restrict__ tgt,
    float* __restrict__ out)
{
    constexpr int   C = 3, H = 512, W = 512;
    constexpr float INV_N     = 1.0f / (C * K * K);              // 1/147
    constexpr float INV_TOTAL = 1.0f / (16.0f * 512.0f * 512.0f);

    const int tid = threadIdx.x;
    const int xg  = tid & 127;          // float4 column group 0..127
    const int x0  = xg << 2;            // first output column
    const int strip = (blockIdx.x << 1) + (tid >> 7);   // wave-uniform
    const int y0  = strip * NY;         // first output row
    const int b   = blockIdx.y;
    const size_t plane = (size_t)H * W;

    const bool leftOK  = (xg > 0);
    const bool rightOK = (xg < 127);
    const float4 z4 = make_float4(0.f, 0.f, 0.f, 0.f);

    const float* base[2] = { pred + (size_t)b * C * plane,
                             tgt  + (size_t)b * C * plane };

    float4 aS[2][NY], aQ[2][NY];
    #pragma unroll
    for (int w = 0; w < 2; ++w)
        #pragma unroll
        for (int j = 0; j < NY; ++j) { aS[w][j] = z4; aQ[w][j] = z4; }

    #pragma unroll
    for (int i = 0; i < NY + 2 * PAD; ++i) {
        const int   gy  = y0 - PAD + i;
        const float m   = ((unsigned)gy < (unsigned)H) ? 1.0f : 0.0f;
        const int   gyc = min(max(gy, 0), H - 1);       // loads always legal

        #pragma unroll
        for (int w = 0; w < 2; ++w) {
            float t[12], t2[12];
            #pragma unroll
            for (int q = 0; q < 12; ++q) { t[q] = 0.f; t2[q] = 0.f; }

            #pragma unroll
            for (int c = 0; c < C; ++c) {
                const float* rp = base[w] + (size_t)c * plane + (size_t)gyc * W + x0;
                float4 va = leftOK  ? *(const float4*)(rp - 4) : z4;
                float4 vb = *(const float4*)(rp);
                float4 vc = rightOK ? *(const float4*)(rp + 4) : z4;
                float v[12] = { va.x, va.y, va.z, va.w,
                                vb.x, vb.y, vb.z, vb.w,
                                vc.x, vc.y, vc.z, vc.w };
                #pragma unroll
                for (int q = 0; q < 12; ++q) {
                    t [q] += v[q];
                    t2[q]  = fmaf(v[q], v[q], t2[q]);
                }
            }

            // sliding 7-tap horizontal window, then null invalid rows (m=0)
            float h0 = t[1] + t[2] + t[3] + t[4] + t[5] + t[6] + t[7];
            float h1 = h0 - t[1] + t[8];
            float h2 = h1 - t[2] + t[9];
            float h3 = h2 - t[3] + t[10];
            float g0 = t2[1] + t2[2] + t2[3] + t2[4] + t2[5] + t2[6] + t2[7];
            float g1 = g0 - t2[1] + t2[8];
            float g2 = g1 - t2[2] + t2[9];
            float g3 = g2 - t2[3] + t2[10];
            h0 *= m; h1 *= m; h2 *= m; h3 *= m;
            g0 *= m; g1 *= m; g2 *= m; g3 *= m;

            // accumulate into overlapping output rows (static bounds)
            #pragma unroll
            for (int j = 0; j < NY; ++j) {
                if (j >= i - (K - 1) && j <= i) {
                    aS[w][j].x += h0; aS[w][j].y += h1;
                    aS[w][j].z += h2; aS[w][j].w += h3;
                    aQ[w][j].x += g0; aQ[w][j].y += g1;
                    aQ[w][j].z += g2; aQ[w][j].w += g3;
                }
            }
        }
    }

    // epilogue: std for both inputs per pixel + smooth-L1
    float acc = 0.0f;
    #pragma unroll
    for (int j = 0; j < NY; ++j) {
        #pragma unroll
        for (int q = 0; q < 4; ++q) {
            float s0  = (&aS[0][j].x)[q], q0 = (&aQ[0][j].x)[q];
            float s1  = (&aS[1][j].x)[q], q1 = (&aQ[1][j].x)[q];
            float mu0 = s0 * INV_N;
            float mu1 = s1 * INV_N;
            float v0  = fmaf(-mu0, mu0, q0 * INV_N);
            float v1  = fmaf(-mu1, mu1, q1 * INV_N);
            float d   = sqrtf(v0 + 1e-8f) - sqrtf(v1 + 1e-8f);
            float ad  = fabsf(d);
            acc += (ad < 1.0f) ? 0.5f * d * d : (ad - 0.5f);
        }
    }

    // block reduction: wave64 shuffle, cross-wave via LDS, one atomic
    #pragma unroll
    for (int off = 32; off > 0; off >>= 1)
        acc += __shfl_down(acc, off, 64);

    __shared__ float wave_sums[NT / 64];
    if ((tid & 63) == 0) wave_sums[tid >> 6] = acc;
    __syncthreads();
    if (tid == 0) {
        float s = 0.0f;
        #pragma unroll
        for (int w = 0; w < NT / 64; ++w) s += wave_sums[w];
        atomicAdd(out, s * INV_TOTAL);
    }
}

extern "C" void kernel_launch(void* const* d_in, const int* in_sizes, int n_in,
                              void* d_out, int out_size, void* d_ws, size_t ws_size,
                              hipStream_t stream) {
    const float* pred = (const float*)d_in[0];
    const float* tgt  = (const float*)d_in[1];
    float* out = (float*)d_out;

    hipMemsetAsync(out, 0, sizeof(float), stream);

    // 64 strip-pairs (512 rows / NY=4 / 2 strips per block) x 16 batches
    dim3 grid(64, 16);
    dist_loss_kernel<<<grid, NT, 0, stream>>>(pred, tgt, out);
}

// Round 5
// 549.948 us; speedup vs baseline: 1.2008x; 1.2008x over previous
//
#include <hip/hip_runtime.h>

// DistributionLoss: local 7x7xC std (zero-padded) of two [16,3,512,512] fp32
// tensors, smooth-L1 mean between std maps -> scalar.
//
// R5: R3's register-resident 4x4-per-thread design made BRANCH-FREE.
//  - gy clamped so loads are always legal; out-of-range rows nulled by a
//    0/1 mask multiply on the row sums (exact: contributions are linear).
//  - No control flow inside the fully-unrolled 10-row loop -> loads from
//    later iterations hoist above earlier compute (cross-iter MLP).
//  - ALL temps are named float4s accessed via .x/.y/.z/.w only. R4 spilled
//    753 MB to scratch because component-pointer addressing on 2-D arrays
//    defeated SROA. Never take addresses of register state.
//  - Inputs processed sequentially (keeps VGPR ~<100, no spill risk).

#define K   7
#define PAD 3
#define NY  4
#define NT  256

__device__ __forceinline__ float4 add3(float4 a, float4 b, float4 c) {
    return make_float4(a.x + b.x + c.x, a.y + b.y + c.y,
                       a.z + b.z + c.z, a.w + b.w + c.w);
}
__device__ __forceinline__ float4 sq3(float4 a, float4 b, float4 c) {
    return make_float4(fmaf(a.x, a.x, fmaf(b.x, b.x, c.x * c.x)),
                       fmaf(a.y, a.y, fmaf(b.y, b.y, c.y * c.y)),
                       fmaf(a.z, a.z, fmaf(b.z, b.z, c.z * c.z)),
                       fmaf(a.w, a.w, fmaf(b.w, b.w, c.w * c.w)));
}

__global__ __launch_bounds__(NT, 4) void dist_loss_kernel(
    const float* __restrict__ pred,
    const float* __restrict__ tgt,
    float* __restrict__ out)
{
    constexpr int   C = 3, H = 512, W = 512;
    constexpr float INV_N     = 1.0f / (C * K * K);              // 1/147
    constexpr float INV_TOTAL = 1.0f / (16.0f * 512.0f * 512.0f);

    const int tid = threadIdx.x;
    const int xg  = tid & 127;          // float4 column group 0..127
    const int x0  = xg << 2;            // first output column
    const int strip = (blockIdx.x << 1) + (tid >> 7);   // wave-uniform
    const int y0  = strip * NY;         // first output row
    const int b   = blockIdx.y;
    const size_t plane = (size_t)H * W;

    const bool leftOK  = (xg > 0);
    const bool rightOK = (xg < 127);
    const float4 z4 = make_float4(0.f, 0.f, 0.f, 0.f);

    float4 p0, p1, p2, p3;              // input 0's std quads
    float  acc = 0.0f;

    #pragma unroll
    for (int which = 0; which < 2; ++which) {
        const float* base = (which == 0 ? pred : tgt) + (size_t)b * C * plane;

        float4 aS0 = z4, aS1 = z4, aS2 = z4, aS3 = z4;   // sum accumulators
        float4 aQ0 = z4, aQ1 = z4, aQ2 = z4, aQ3 = z4;   // sum-sq accumulators

        #pragma unroll
        for (int i = 0; i < NY + 2 * PAD; ++i) {
            const int   gy  = y0 - PAD + i;
            const float m   = ((unsigned)gy < (unsigned)H) ? 1.0f : 0.0f;
            const int   gyc = min(max(gy, 0), H - 1);    // loads always legal
            const float* r0 = base + (size_t)gyc * W + x0;
            const float* r1 = r0 + plane;
            const float* r2 = r1 + plane;

            float4 A0 = leftOK  ? *(const float4*)(r0 - 4) : z4;
            float4 B0 = *(const float4*)(r0);
            float4 C0 = rightOK ? *(const float4*)(r0 + 4) : z4;
            float4 A1 = leftOK  ? *(const float4*)(r1 - 4) : z4;
            float4 B1 = *(const float4*)(r1);
            float4 C1 = rightOK ? *(const float4*)(r1 + 4) : z4;
            float4 A2 = leftOK  ? *(const float4*)(r2 - 4) : z4;
            float4 B2 = *(const float4*)(r2);
            float4 C2 = rightOK ? *(const float4*)(r2 + 4) : z4;

            float4 tl = add3(A0, A1, A2);
            float4 tm = add3(B0, B1, B2);
            float4 tr = add3(C0, C1, C2);
            float4 ul = sq3(A0, A1, A2);
            float4 um = sq3(B0, B1, B2);
            float4 ur = sq3(C0, C1, C2);

            // sliding 7-tap horizontal window: outputs x0..x0+3
            float h0 = tl.y + tl.z + tl.w + tm.x + tm.y + tm.z + tm.w;
            float h1 = h0 - tl.y + tr.x;
            float h2 = h1 - tl.z + tr.y;
            float h3 = h2 - tl.w + tr.z;
            float g0 = ul.y + ul.z + ul.w + um.x + um.y + um.z + um.w;
            float g1 = g0 - ul.y + ur.x;
            float g2 = g1 - ul.z + ur.y;
            float g3 = g2 - ul.w + ur.z;
            h0 *= m; h1 *= m; h2 *= m; h3 *= m;
            g0 *= m; g1 *= m; g2 *= m; g3 *= m;

            // accumulate into overlapping output rows (conditions fold:
            // i is a constant after full unroll)
            if (i <= 6) {             // row 0: i in [0,6]
                aS0.x += h0; aS0.y += h1; aS0.z += h2; aS0.w += h3;
                aQ0.x += g0; aQ0.y += g1; aQ0.z += g2; aQ0.w += g3;
            }
            if (i >= 1 && i <= 7) {   // row 1
                aS1.x += h0; aS1.y += h1; aS1.z += h2; aS1.w += h3;
                aQ1.x += g0; aQ1.y += g1; aQ1.z += g2; aQ1.w += g3;
            }
            if (i >= 2 && i <= 8) {   // row 2
                aS2.x += h0; aS2.y += h1; aS2.z += h2; aS2.w += h3;
                aQ2.x += g0; aQ2.y += g1; aQ2.z += g2; aQ2.w += g3;
            }
            if (i >= 3) {             // row 3: i in [3,9]
                aS3.x += h0; aS3.y += h1; aS3.z += h2; aS3.w += h3;
                aQ3.x += g0; aQ3.y += g1; aQ3.z += g2; aQ3.w += g3;
            }
        }

        // epilogue: std per pixel (explicit components only)
        #define STD4(S, Q, D)                                                 \
            {                                                                 \
                float mux = (S).x * INV_N, muy = (S).y * INV_N,               \
                      muz = (S).z * INV_N, muw = (S).w * INV_N;               \
                (D).x = sqrtf(fmaf(-mux, mux, (Q).x * INV_N) + 1e-8f);        \
                (D).y = sqrtf(fmaf(-muy, muy, (Q).y * INV_N) + 1e-8f);        \
                (D).z = sqrtf(fmaf(-muz, muz, (Q).z * INV_N) + 1e-8f);        \
                (D).w = sqrtf(fmaf(-muw, muw, (Q).w * INV_N) + 1e-8f);        \
            }
        #define SL1(a, b)                                                     \
            {                                                                 \
                float d = (a) - (b);                                          \
                float ad = fabsf(d);                                          \
                acc += (ad < 1.0f) ? 0.5f * d * d : (ad - 0.5f);              \
            }

        if (which == 0) {
            STD4(aS0, aQ0, p0); STD4(aS1, aQ1, p1);
            STD4(aS2, aQ2, p2); STD4(aS3, aQ3, p3);
        } else {
            float4 s0, s1, s2, s3;
            STD4(aS0, aQ0, s0); STD4(aS1, aQ1, s1);
            STD4(aS2, aQ2, s2); STD4(aS3, aQ3, s3);
            SL1(p0.x, s0.x); SL1(p0.y, s0.y); SL1(p0.z, s0.z); SL1(p0.w, s0.w);
            SL1(p1.x, s1.x); SL1(p1.y, s1.y); SL1(p1.z, s1.z); SL1(p1.w, s1.w);
            SL1(p2.x, s2.x); SL1(p2.y, s2.y); SL1(p2.z, s2.z); SL1(p2.w, s2.w);
            SL1(p3.x, s3.x); SL1(p3.y, s3.y); SL1(p3.z, s3.z); SL1(p3.w, s3.w);
        }
        #undef STD4
        #undef SL1
    }

    // block reduction: wave64 shuffle, cross-wave via LDS, one atomic
    #pragma unroll
    for (int off = 32; off > 0; off >>= 1)
        acc += __shfl_down(acc, off, 64);

    __shared__ float wave_sums[NT / 64];
    if ((tid & 63) == 0) wave_sums[tid >> 6] = acc;
    __syncthreads();
    if (tid == 0) {
        float s = 0.0f;
        #pragma unroll
        for (int w = 0; w < NT / 64; ++w) s += wave_sums[w];
        atomicAdd(out, s * INV_TOTAL);
    }
}

extern "C" void kernel_launch(void* const* d_in, const int* in_sizes, int n_in,
                              void* d_out, int out_size, void* d_ws, size_t ws_size,
                              hipStream_t stream) {
    const float* pred = (const float*)d_in[0];
    const float* tgt  = (const float*)d_in[1];
    float* out = (float*)d_out;

    hipMemsetAsync(out, 0, sizeof(float), stream);

    // 64 strip-pairs (512 rows / NY=4 / 2 strips per block) x 16 batches
    dim3 grid(64, 16);
    dist_loss_kernel<<<grid, NT, 0, stream>>>(pred, tgt, out);
}

// Round 6
// 401.373 us; speedup vs baseline: 1.6453x; 1.3702x over previous
//
#include <hip/hip_runtime.h>

// DistributionLoss: local 7x7xC std (zero-padded) of two [16,3,512,512] fp32
// tensors, smooth-L1 mean between std maps -> scalar.
//
// R6: R5 (branch-free register-resident 4x4-per-thread) with the VGPR cap
// raised: __launch_bounds__(256, 2) -> 256-VGPR budget. R4/R5 spilled
// ~680 MB/dispatch because the allocator pinned VGPRs at 64 (8-waves/EU
// occupancy target) and spilled the ~100-reg live state instead of
// relaxing occupancy. Natural pressure fits under 256 with zero spills;
// pressure-based occupancy still ~16 waves/CU.

#define K   7
#define PAD 3
#define NY  4
#define NT  256

__device__ __forceinline__ float4 add3(float4 a, float4 b, float4 c) {
    return make_float4(a.x + b.x + c.x, a.y + b.y + c.y,
                       a.z + b.z + c.z, a.w + b.w + c.w);
}
__device__ __forceinline__ float4 sq3(float4 a, float4 b, float4 c) {
    return make_float4(fmaf(a.x, a.x, fmaf(b.x, b.x, c.x * c.x)),
                       fmaf(a.y, a.y, fmaf(b.y, b.y, c.y * c.y)),
                       fmaf(a.z, a.z, fmaf(b.z, b.z, c.z * c.z)),
                       fmaf(a.w, a.w, fmaf(b.w, b.w, c.w * c.w)));
}

__global__ __launch_bounds__(NT, 2) void dist_loss_kernel(
    const float* __restrict__ pred,
    const float* __restrict__ tgt,
    float* __restrict__ out)
{
    constexpr int   C = 3, H = 512, W = 512;
    constexpr float INV_N     = 1.0f / (C * K * K);              // 1/147
    constexpr float INV_TOTAL = 1.0f / (16.0f * 512.0f * 512.0f);

    const int tid = threadIdx.x;
    const int xg  = tid & 127;          // float4 column group 0..127
    const int x0  = xg << 2;            // first output column
    const int strip = (blockIdx.x << 1) + (tid >> 7);   // wave-uniform
    const int y0  = strip * NY;         // first output row
    const int b   = blockIdx.y;
    const size_t plane = (size_t)H * W;

    const bool leftOK  = (xg > 0);
    const bool rightOK = (xg < 127);
    const float4 z4 = make_float4(0.f, 0.f, 0.f, 0.f);

    float4 p0, p1, p2, p3;              // input 0's std quads
    float  acc = 0.0f;

    #pragma unroll
    for (int which = 0; which < 2; ++which) {
        const float* base = (which == 0 ? pred : tgt) + (size_t)b * C * plane;

        float4 aS0 = z4, aS1 = z4, aS2 = z4, aS3 = z4;   // sum accumulators
        float4 aQ0 = z4, aQ1 = z4, aQ2 = z4, aQ3 = z4;   // sum-sq accumulators

        #pragma unroll
        for (int i = 0; i < NY + 2 * PAD; ++i) {
            const int   gy  = y0 - PAD + i;
            const float m   = ((unsigned)gy < (unsigned)H) ? 1.0f : 0.0f;
            const int   gyc = min(max(gy, 0), H - 1);    // loads always legal
            const float* r0 = base + (size_t)gyc * W + x0;
            const float* r1 = r0 + plane;
            const float* r2 = r1 + plane;

            float4 A0 = leftOK  ? *(const float4*)(r0 - 4) : z4;
            float4 B0 = *(const float4*)(r0);
            float4 C0 = rightOK ? *(const float4*)(r0 + 4) : z4;
            float4 A1 = leftOK  ? *(const float4*)(r1 - 4) : z4;
            float4 B1 = *(const float4*)(r1);
            float4 C1 = rightOK ? *(const float4*)(r1 + 4) : z4;
            float4 A2 = leftOK  ? *(const float4*)(r2 - 4) : z4;
            float4 B2 = *(const float4*)(r2);
            float4 C2 = rightOK ? *(const float4*)(r2 + 4) : z4;

            float4 tl = add3(A0, A1, A2);
            float4 tm = add3(B0, B1, B2);
            float4 tr = add3(C0, C1, C2);
            float4 ul = sq3(A0, A1, A2);
            float4 um = sq3(B0, B1, B2);
            float4 ur = sq3(C0, C1, C2);

            // sliding 7-tap horizontal window: outputs x0..x0+3
            float h0 = tl.y + tl.z + tl.w + tm.x + tm.y + tm.z + tm.w;
            float h1 = h0 - tl.y + tr.x;
            float h2 = h1 - tl.z + tr.y;
            float h3 = h2 - tl.w + tr.z;
            float g0 = ul.y + ul.z + ul.w + um.x + um.y + um.z + um.w;
            float g1 = g0 - ul.y + ur.x;
            float g2 = g1 - ul.z + ur.y;
            float g3 = g2 - ul.w + ur.z;
            h0 *= m; h1 *= m; h2 *= m; h3 *= m;
            g0 *= m; g1 *= m; g2 *= m; g3 *= m;

            // accumulate into overlapping output rows (conditions fold:
            // i is a constant after full unroll)
            if (i <= 6) {             // row 0: i in [0,6]
                aS0.x += h0; aS0.y += h1; aS0.z += h2; aS0.w += h3;
                aQ0.x += g0; aQ0.y += g1; aQ0.z += g2; aQ0.w += g3;
            }
            if (i >= 1 && i <= 7) {   // row 1
                aS1.x += h0; aS1.y += h1; aS1.z += h2; aS1.w += h3;
                aQ1.x += g0; aQ1.y += g1; aQ1.z += g2; aQ1.w += g3;
            }
            if (i >= 2 && i <= 8) {   // row 2
                aS2.x += h0; aS2.y += h1; aS2.z += h2; aS2.w += h3;
                aQ2.x += g0; aQ2.y += g1; aQ2.z += g2; aQ2.w += g3;
            }
            if (i >= 3) {             // row 3: i in [3,9]
                aS3.x += h0; aS3.y += h1; aS3.z += h2; aS3.w += h3;
                aQ3.x += g0; aQ3.y += g1; aQ3.z += g2; aQ3.w += g3;
            }
        }

        // epilogue: std per pixel (explicit components only)
        #define STD4(S, Q, D)                                                 \
            {                                                                 \
                float mux = (S).x * INV_N, muy = (S).y * INV_N,               \
                      muz = (S).z * INV_N, muw = (S).w * INV_N;               \
                (D).x = sqrtf(fmaf(-mux, mux, (Q).x * INV_N) + 1e-8f);        \
                (D).y = sqrtf(fmaf(-muy, muy, (Q).y * INV_N) + 1e-8f);        \
                (D).z = sqrtf(fmaf(-muz, muz, (Q).z * INV_N) + 1e-8f);        \
                (D).w = sqrtf(fmaf(-muw, muw, (Q).w * INV_N) + 1e-8f);        \
            }
        #define SL1(a, b)                                                     \
            {                                                                 \
                float d = (a) - (b);                                          \
                float ad = fabsf(d);                                          \
                acc += (ad < 1.0f) ? 0.5f * d * d : (ad - 0.5f);              \
            }

        if (which == 0) {
            STD4(aS0, aQ0, p0); STD4(aS1, aQ1, p1);
            STD4(aS2, aQ2, p2); STD4(aS3, aQ3, p3);
        } else {
            float4 s0, s1, s2, s3;
            STD4(aS0, aQ0, s0); STD4(aS1, aQ1, s1);
            STD4(aS2, aQ2, s2); STD4(aS3, aQ3, s3);
            SL1(p0.x, s0.x); SL1(p0.y, s0.y); SL1(p0.z, s0.z); SL1(p0.w, s0.w);
            SL1(p1.x, s1.x); SL1(p1.y, s1.y); SL1(p1.z, s1.z); SL1(p1.w, s1.w);
            SL1(p2.x, s2.x); SL1(p2.y, s2.y); SL1(p2.z, s2.z); SL1(p2.w, s2.w);
            SL1(p3.x, s3.x); SL1(p3.y, s3.y); SL1(p3.z, s3.z); SL1(p3.w, s3.w);
        }
        #undef STD4
        #undef SL1
    }

    // block reduction: wave64 shuffle, cross-wave via LDS, one atomic
    #pragma unroll
    for (int off = 32; off > 0; off >>= 1)
        acc += __shfl_down(acc, off, 64);

    __shared__ float wave_sums[NT / 64];
    if ((tid & 63) == 0) wave_sums[tid >> 6] = acc;
    __syncthreads();
    if (tid == 0) {
        float s = 0.0f;
        #pragma unroll
        for (int w = 0; w < NT / 64; ++w) s += wave_sums[w];
        atomicAdd(out, s * INV_TOTAL);
    }
}

extern "C" void kernel_launch(void* const* d_in, const int* in_sizes, int n_in,
                              void* d_out, int out_size, void* d_ws, size_t ws_size,
                              hipStream_t stream) {
    const float* pred = (const float*)d_in[0];
    const float* tgt  = (const float*)d_in[1];
    float* out = (float*)d_out;

    hipMemsetAsync(out, 0, sizeof(float), stream);

    // 64 strip-pairs (512 rows / NY=4 / 2 strips per block) x 16 batches
    dim3 grid(64, 16);
    dist_loss_kernel<<<grid, NT, 0, stream>>>(pred, tgt, out);
}

// Round 7
// 144.132 us; speedup vs baseline: 4.5818x; 2.7848x over previous
//
#include <hip/hip_runtime.h>

// DistributionLoss: local 7x7xC std (zero-padded) of two [16,3,512,512] fp32
// tensors, smooth-L1 mean between std maps -> scalar.
//
// R7: two-phase LDS design, ONE LDS round-trip per input.
//  Phase A: each task (row, colgroup) does 9 aligned float4 global loads
//   (3 ch x 3 groups; L1 absorbs the 3x horizontal overlap), channel-reduces,
//   computes the horizontal 7-tap sliding window, and writes h/g straight to
//   LDS. OOB rows nulled by 0/1 mask multiply (exact: linear); OOB columns
//   zeroed by cndmask. Compact dynamic task loop -> bounded VGPR, no spill
//   (R4-R6 lesson: full-unroll register designs explode to ~300 live regs).
//  Phase B: vertical 7-tap from LDS (2 rows/thread via y-sliding), std,
//   input 0 parks in regs, input 1 fuses smooth-L1.
//  2 barriers per input; 20.7 KB LDS -> ~6 blocks/CU co-resident to cover
//  barrier stalls.

#define K     7
#define PAD   3
#define TSX   64
#define TSY   32
#define HR    (TSY + K - 1)   // 38 halo rows
#define LDSW  68              // LDS row stride (floats); 64 data + 4 pad
#define NT    256

__device__ __forceinline__ float4 add3(float4 a, float4 b, float4 c) {
    return make_float4(a.x + b.x + c.x, a.y + b.y + c.y,
                       a.z + b.z + c.z, a.w + b.w + c.w);
}
__device__ __forceinline__ float4 sq3(float4 a, float4 b, float4 c) {
    return make_float4(fmaf(a.x, a.x, fmaf(b.x, b.x, c.x * c.x)),
                       fmaf(a.y, a.y, fmaf(b.y, b.y, c.y * c.y)),
                       fmaf(a.z, a.z, fmaf(b.z, b.z, c.z * c.z)),
                       fmaf(a.w, a.w, fmaf(b.w, b.w, c.w * c.w)));
}

__global__ __launch_bounds__(NT, 4) void dist_loss_kernel(
    const float* __restrict__ pred,
    const float* __restrict__ tgt,
    float* __restrict__ out)
{
    constexpr int   C = 3, H = 512, W = 512;
    constexpr float INV_N     = 1.0f / (C * K * K);              // 1/147
    constexpr float INV_TOTAL = 1.0f / (16.0f * 512.0f * 512.0f);

    __shared__ float sh_s[HR][LDSW];   // horizontal 7-tap of channel sum
    __shared__ float sh_q[HR][LDSW];   // horizontal 7-tap of channel sum-sq

    const int    tid  = threadIdx.x;
    const int    tx0  = blockIdx.x * TSX;
    const int    ty0  = blockIdx.y * TSY;
    const int    b    = blockIdx.z;
    const size_t plane = (size_t)H * W;
    const float4 z4 = make_float4(0.f, 0.f, 0.f, 0.f);

    float4 pA, pB;            // input 0's std quads (rows 2rp, 2rp+1)
    float  acc = 0.0f;

    #pragma unroll
    for (int which = 0; which < 2; ++which) {
        const float* base = (which == 0 ? pred : tgt) + (size_t)b * C * plane;

        // ---- Phase A: global -> horizontal 7-tap -> LDS (h, g)
        for (int task = tid; task < HR * 16; task += NT) {
            const int   row = task >> 4;                 // 0..37
            const int   cg  = task & 15;
            const int   gy  = ty0 - PAD + row;
            const float m   = ((unsigned)gy < (unsigned)H) ? 1.0f : 0.0f;
            const int   gyc = min(max(gy, 0), H - 1);    // loads always legal
            const int   gx0 = tx0 + (cg << 2);
            const bool  leftOK  = (gx0 > 0);
            const bool  rightOK = (gx0 < 508);

            const float* r0 = base + (size_t)gyc * W + gx0;
            const float* r1 = r0 + plane;
            const float* r2 = r1 + plane;

            float4 A0 = leftOK  ? *(const float4*)(r0 - 4) : z4;
            float4 B0 = *(const float4*)(r0);
            float4 C0 = rightOK ? *(const float4*)(r0 + 4) : z4;
            float4 A1 = leftOK  ? *(const float4*)(r1 - 4) : z4;
            float4 B1 = *(const float4*)(r1);
            float4 C1 = rightOK ? *(const float4*)(r1 + 4) : z4;
            float4 A2 = leftOK  ? *(const float4*)(r2 - 4) : z4;
            float4 B2 = *(const float4*)(r2);
            float4 C2 = rightOK ? *(const float4*)(r2 + 4) : z4;

            float4 tl = add3(A0, A1, A2);
            float4 tm = add3(B0, B1, B2);
            float4 tr = add3(C0, C1, C2);
            float4 ul = sq3(A0, A1, A2);
            float4 um = sq3(B0, B1, B2);
            float4 ur = sq3(C0, C1, C2);

            // sliding 7-tap horizontal window for out cols gx0..gx0+3
            float h0 = tl.y + tl.z + tl.w + tm.x + tm.y + tm.z + tm.w;
            float h1 = h0 - tl.y + tr.x;
            float h2 = h1 - tl.z + tr.y;
            float h3 = h2 - tl.w + tr.z;
            float g0 = ul.y + ul.z + ul.w + um.x + um.y + um.z + um.w;
            float g1 = g0 - ul.y + ur.x;
            float g2 = g1 - ul.z + ur.y;
            float g3 = g2 - ul.w + ur.z;

            *(float4*)&sh_s[row][cg << 2] =
                make_float4(h0 * m, h1 * m, h2 * m, h3 * m);
            *(float4*)&sh_q[row][cg << 2] =
                make_float4(g0 * m, g1 * m, g2 * m, g3 * m);
        }
        __syncthreads();

        // ---- Phase B: vertical 7-tap + std; 2 output rows per thread
        {
            const int rp = tid >> 4;          // row pair 0..15
            const int x  = (tid & 15) << 2;   // col within tile

            float4 S = z4, Q = z4;
            #pragma unroll
            for (int k = 0; k < K; ++k) {
                float4 hv = *(const float4*)&sh_s[2 * rp + k][x];
                float4 gv = *(const float4*)&sh_q[2 * rp + k][x];
                S.x += hv.x; S.y += hv.y; S.z += hv.z; S.w += hv.w;
                Q.x += gv.x; Q.y += gv.y; Q.z += gv.z; Q.w += gv.w;
            }
            float4 hA = *(const float4*)&sh_s[2 * rp][x];
            float4 gA = *(const float4*)&sh_q[2 * rp][x];
            float4 hB = *(const float4*)&sh_s[2 * rp + 7][x];
            float4 gB = *(const float4*)&sh_q[2 * rp + 7][x];
            float4 S2 = make_float4(S.x - hA.x + hB.x, S.y - hA.y + hB.y,
                                    S.z - hA.z + hB.z, S.w - hA.w + hB.w);
            float4 Q2 = make_float4(Q.x - gA.x + gB.x, Q.y - gA.y + gB.y,
                                    Q.z - gA.z + gB.z, Q.w - gA.w + gB.w);

            #define STD4(Sv, Qv, D)                                           \
                {                                                             \
                    float mux = (Sv).x * INV_N, muy = (Sv).y * INV_N,         \
                          muz = (Sv).z * INV_N, muw = (Sv).w * INV_N;         \
                    (D).x = sqrtf(fmaf(-mux, mux, (Qv).x * INV_N) + 1e-8f);   \
                    (D).y = sqrtf(fmaf(-muy, muy, (Qv).y * INV_N) + 1e-8f);   \
                    (D).z = sqrtf(fmaf(-muz, muz, (Qv).z * INV_N) + 1e-8f);   \
                    (D).w = sqrtf(fmaf(-muw, muw, (Qv).w * INV_N) + 1e-8f);   \
                }
            #define SL1(a, bb)                                                \
                {                                                             \
                    float d  = (a) - (bb);                                    \
                    float ad = fabsf(d);                                      \
                    acc += (ad < 1.0f) ? 0.5f * d * d : (ad - 0.5f);          \
                }

            if (which == 0) {
                STD4(S, Q, pA);
                STD4(S2, Q2, pB);
            } else {
                float4 sA, sB;
                STD4(S, Q, sA);
                STD4(S2, Q2, sB);
                SL1(pA.x, sA.x); SL1(pA.y, sA.y);
                SL1(pA.z, sA.z); SL1(pA.w, sA.w);
                SL1(pB.x, sB.x); SL1(pB.y, sB.y);
                SL1(pB.z, sB.z); SL1(pB.w, sB.w);
            }
            #undef STD4
            #undef SL1
        }
        __syncthreads();   // protect sh_s/sh_q before next input's phase A
    }

    // ---- block reduction: wave64 shuffle, cross-wave via LDS, one atomic
    #pragma unroll
    for (int off = 32; off > 0; off >>= 1)
        acc += __shfl_down(acc, off, 64);

    __shared__ float wave_sums[NT / 64];
    if ((tid & 63) == 0) wave_sums[tid >> 6] = acc;
    __syncthreads();
    if (tid == 0) {
        float s = 0.0f;
        #pragma unroll
        for (int w = 0; w < NT / 64; ++w) s += wave_sums[w];
        atomicAdd(out, s * INV_TOTAL);
    }
}

extern "C" void kernel_launch(void* const* d_in, const int* in_sizes, int n_in,
                              void* d_out, int out_size, void* d_ws, size_t ws_size,
                              hipStream_t stream) {
    const float* pred = (const float*)d_in[0];
    const float* tgt  = (const float*)d_in[1];
    float* out = (float*)d_out;

    hipMemsetAsync(out, 0, sizeof(float), stream);

    dim3 grid(512 / TSX, 512 / TSY, 16);   // 8 x 16 x 16 = 2048 blocks
    dist_loss_kernel<<<grid, NT, 0, stream>>>(pred, tgt, out);
}